// Round 9
// baseline (166.124 us; speedup 1.0000x reference)
//
#include <hip/hip_runtime.h>
#include <hip/hip_bf16.h>

#define BATCH 64
#define UNITS 1024
#define CHUNK 8192
#define NSPLIT 4       // WGs per column in gather
#define NZERO 16       // WGs in prep that zero `out`

typedef unsigned int u32;
typedef unsigned short u16;

// ---------------- zero helper (fallback path C only) -----------------------
__global__ __launch_bounds__(256)
void zero4_kernel(uint4* __restrict__ p, int n4) {
    int i = blockIdx.x * 256 + threadIdx.x;
    const int stride = gridDim.x * 256;
    const uint4 z = make_uint4(0u, 0u, 0u, 0u);
    for (; i < n4; i += stride) p[i] = z;
}

// ---- fused: zero out  |  transpose x -> bf16 xT  |  per-chunk histogram ---
// blocks [0,nZ): zero out.  [nZ,nZ+nT): transpose slab.  rest: histogram.
__global__ __launch_bounds__(256)
void prep_kernel(const float* __restrict__ x, u16* __restrict__ xT,
                 const int* __restrict__ col, u32* __restrict__ hist2,
                 float* __restrict__ out, int nfeat, int nZ, int nT, int nnz) {
    __shared__ float tile[64][65];
    __shared__ u32 lh[UNITS];
    const int bid = blockIdx.x;
    const int tid = threadIdx.x;
    if (bid < nZ) {
        uint4* o4 = (uint4*)out;
        const uint4 z = make_uint4(0u, 0u, 0u, 0u);
        const int n4 = (BATCH * UNITS) / 4;              // 16384 uint4
        for (int i = bid * 256 + tid; i < n4; i += nZ * 256) o4[i] = z;
    } else if (bid < nZ + nT) {
        const int c0 = (bid - nZ) * 64;
        const int tx = tid & 63, ty = tid >> 6;
        for (int b = ty; b < 64; b += 4) {
            int c = c0 + tx;
            if (c < nfeat) tile[b][tx] = x[(size_t)b * nfeat + c];   // coalesced
        }
        __syncthreads();
        for (int i = ty; i < 64; i += 4) {
            int c = c0 + i;
            if (c < nfeat) {
                __hip_bfloat16 h = __float2bfloat16(tile[tx][i]);
                xT[(size_t)c * 64 + tx] = *(u16*)&h;                 // coalesced
            }
        }
    } else {
        const int g = bid - nZ - nT;
        for (int i = tid; i < UNITS; i += 256) lh[i] = 0u;
        __syncthreads();
        const int g0 = g * CHUNK;
        const int n = min(CHUNK, nnz - g0);
        for (int i = tid; i < n; i += 256)
            atomicAdd(&lh[col[g0 + i]], 1u);
        __syncthreads();
        for (int c = tid; c < UNITS; c += 256)
            hist2[(size_t)g * UNITS + c] = lh[c];
    }
}

// ---- scan: column exclusive scan + FULL per-chunk base matrix -------------
// One WG, 1024 threads (thread = column). Serial chunk loop is coalesced row
// loads/stores, pipelined x4. Writing base2 here deletes reorder's 30 MB
// hist2 re-read prologue.
__global__ __launch_bounds__(1024)
void scan_kernel(const u32* __restrict__ hist2, u32* __restrict__ base2,
                 u32* __restrict__ col_start, int nchunk) {
    const int c = threadIdx.x;
    u32 tot = 0;
    int g = 0;
    for (; g + 8 <= nchunk; g += 8) {
        u32 h0 = hist2[(size_t)(g + 0) * UNITS + c];
        u32 h1 = hist2[(size_t)(g + 1) * UNITS + c];
        u32 h2 = hist2[(size_t)(g + 2) * UNITS + c];
        u32 h3 = hist2[(size_t)(g + 3) * UNITS + c];
        u32 h4 = hist2[(size_t)(g + 4) * UNITS + c];
        u32 h5 = hist2[(size_t)(g + 5) * UNITS + c];
        u32 h6 = hist2[(size_t)(g + 6) * UNITS + c];
        u32 h7 = hist2[(size_t)(g + 7) * UNITS + c];
        tot += ((h0 + h1) + (h2 + h3)) + ((h4 + h5) + (h6 + h7));
    }
    for (; g < nchunk; ++g) tot += hist2[(size_t)g * UNITS + c];
    __shared__ u32 a[UNITS];
    a[c] = tot;
    __syncthreads();
    for (int off = 1; off < UNITS; off <<= 1) {
        u32 add = (c >= off) ? a[c - off] : 0u;
        u32 v = a[c];
        __syncthreads();
        a[c] = v + add;
        __syncthreads();
    }
    u32 run = a[c] - tot;                    // exclusive column prefix
    col_start[c] = run;
    if (c == UNITS - 1) col_start[UNITS] = a[UNITS - 1];
    g = 0;
    for (; g + 4 <= nchunk; g += 4) {
        u32 h0 = hist2[(size_t)(g + 0) * UNITS + c];
        u32 h1 = hist2[(size_t)(g + 1) * UNITS + c];
        u32 h2 = hist2[(size_t)(g + 2) * UNITS + c];
        u32 h3 = hist2[(size_t)(g + 3) * UNITS + c];
        base2[(size_t)(g + 0) * UNITS + c] = run; run += h0;
        base2[(size_t)(g + 1) * UNITS + c] = run; run += h1;
        base2[(size_t)(g + 2) * UNITS + c] = run; run += h2;
        base2[(size_t)(g + 3) * UNITS + c] = run; run += h3;
    }
    for (; g < nchunk; ++g) {
        base2[(size_t)g * UNITS + c] = run;
        run += hist2[(size_t)g * UNITS + c];
    }
}

// ---- reorder: pack (bf16(w)<<16 | row) into column bins -------------------
// Base comes straight from base2 (one coalesced row load). LDS atomics only.
__global__ __launch_bounds__(512)
void reorder_kernel(const int* __restrict__ row, const int* __restrict__ col,
                    const float* __restrict__ w, const u32* __restrict__ base2,
                    u32* __restrict__ sorted, int nnz) {
    __shared__ u32 cur[UNITS];
    const int tid = threadIdx.x;
    const int g = blockIdx.x;
    for (int c = tid; c < UNITS; c += 512)
        cur[c] = base2[(size_t)g * UNITS + c];
    __syncthreads();
    const int g0 = g * CHUNK;
    const int n = min(CHUNK, nnz - g0);
    if (n == CHUNK) {
        for (int j2 = 0; j2 < CHUNK / 512; j2 += 8) {     // 2 batches of 8
            u32 cc[8], pk[8], lo[8];
#pragma unroll
            for (int q = 0; q < 8; ++q) {
                const int k = g0 + tid + 512 * (j2 + q);
                cc[q] = (u32)col[k];
                __hip_bfloat16 h = __float2bfloat16(w[k]);
                pk[q] = ((u32)(*(const u16*)&h) << 16) | (u32)row[k];
            }
#pragma unroll
            for (int q = 0; q < 8; ++q) lo[q] = atomicAdd(&cur[cc[q]], 1u);
#pragma unroll
            for (int q = 0; q < 8; ++q) sorted[lo[q]] = pk[q];
        }
    } else {
        for (int i = tid; i < n; i += 512) {
            const int k = g0 + i;
            const u32 c = (u32)col[k];
            __hip_bfloat16 h = __float2bfloat16(w[k]);
            const u32 pk = ((u32)(*(const u16*)&h) << 16) | (u32)row[k];
            const u32 lo = atomicAdd(&cur[c], 1u);
            sorted[lo] = pk;
        }
    }
}

// ---- gather: NSPLIT WGs per column, 64 batches = 64 lanes -----------------
// Uniform-pointer addressing: readlane entry -> SGPR row base; per-lane
// voffset (lane*2) loop-invariant. Partials combined via unsafeAtomicAdd
// into out (pre-zeroed by prep).
__global__ __launch_bounds__(256)
void gather_kernel(const u16* __restrict__ xTu, const u32* __restrict__ sorted,
                   const u32* __restrict__ col_start, float* __restrict__ out) {
    const int u = blockIdx.x >> 2;          // column
    const int part = blockIdx.x & 3;        // NSPLIT=4
    const int tid = threadIdx.x;
    const int wv = tid >> 6, lane = tid & 63;   // lane = batch
    const u32 s = col_start[u], e = col_start[u + 1];
    float acc0 = 0.f, acc1 = 0.f, acc2 = 0.f, acc3 = 0.f;
    for (u32 b0 = s + (u32)(part * 4 + wv) * 64u; b0 < e; b0 += (u32)(NSPLIT * 4) * 64u) {
        u32 pk = 0u;                                 // pad: w=+0 -> no-op
        if (b0 + (u32)lane < e) pk = sorted[b0 + (u32)lane];
#pragma unroll
        for (int t = 0; t < 64; t += 4) {
            const u32 e0 = (u32)__builtin_amdgcn_readlane((int)pk, t);
            const u32 e1 = (u32)__builtin_amdgcn_readlane((int)pk, t + 1);
            const u32 e2 = (u32)__builtin_amdgcn_readlane((int)pk, t + 2);
            const u32 e3 = (u32)__builtin_amdgcn_readlane((int)pk, t + 3);
            const u16* p0 = xTu + ((e0 & 0xffffu) << 6);   // wave-uniform base
            const u16* p1 = xTu + ((e1 & 0xffffu) << 6);
            const u16* p2 = xTu + ((e2 & 0xffffu) << 6);
            const u16* p3 = xTu + ((e3 & 0xffffu) << 6);
            const float x0 = __uint_as_float(((u32)p0[lane]) << 16);
            const float x1 = __uint_as_float(((u32)p1[lane]) << 16);
            const float x2 = __uint_as_float(((u32)p2[lane]) << 16);
            const float x3 = __uint_as_float(((u32)p3[lane]) << 16);
            acc0 = fmaf(x0, __uint_as_float(e0 & 0xffff0000u), acc0);
            acc1 = fmaf(x1, __uint_as_float(e1 & 0xffff0000u), acc1);
            acc2 = fmaf(x2, __uint_as_float(e2 & 0xffff0000u), acc2);
            acc3 = fmaf(x3, __uint_as_float(e3 & 0xffff0000u), acc3);
        }
    }
    float tot = (acc0 + acc1) + (acc2 + acc3);
    __shared__ float red[4][64];
    red[wv][lane] = tot;
    __syncthreads();
    if (wv == 0)
        unsafeAtomicAdd(&out[(size_t)lane * UNITS + u],
                        red[0][lane] + red[1][lane] + red[2][lane] + red[3][lane]);
}

// ---------------- small-ws fallbacks ---------------------------------------
__global__ __launch_bounds__(1024, 1)
void scatter_fallback_kernel(const u16* __restrict__ xT, const float* __restrict__ w,
                             const int* __restrict__ row_idx, const int* __restrict__ col_idx,
                             float* __restrict__ out, int nnz) {
    extern __shared__ float priv[];
    const int tid = threadIdx.x;
    for (int i = tid; i < 32 * UNITS; i += 1024) priv[i] = 0.0f;
    __syncthreads();
    const int bid = blockIdx.x, half = bid >> 7, wgIdx = bid & 127;
    const int wave = tid >> 6, lane = tid & 63, h = lane >> 5, bl = lane & 31;
    const int per = (nnz + 127) >> 7;
    const int k0 = wgIdx * per, kend = min(k0 + per, nnz);
    const u16* xTh = xT + half * 32 + bl;
    for (int k = k0 + wave * 2 + h; k < kend; k += 32) {
        const int r = row_idx[k], c = col_idx[k];
        const float xv = __uint_as_float(((u32)xTh[(size_t)r * 64]) << 16);
        atomicAdd(&priv[c * 32 + bl], xv * w[k]);
    }
    __syncthreads();
    for (int i = tid; i < 32 * UNITS; i += 1024) {
        int c = i >> 5, b = half * 32 + (i & 31);
        unsafeAtomicAdd(&out[b * UNITS + c], priv[i]);
    }
}

__global__ __launch_bounds__(256)
void fallback_kernel(const float* __restrict__ x, const float* __restrict__ w,
                     const int* __restrict__ row_idx, const int* __restrict__ col_idx,
                     float* __restrict__ out, int nnz, int nfeat) {
    const int nwaves = (gridDim.x * blockDim.x) >> 6;
    const int wid = (blockIdx.x * blockDim.x + threadIdx.x) >> 6;
    const int lane = threadIdx.x & 63;
    for (int k = wid; k < nnz; k += nwaves) {
        const int r = row_idx[k], c = col_idx[k];
        unsafeAtomicAdd(&out[lane * UNITS + c], x[(size_t)lane * nfeat + r] * w[k]);
    }
}

static inline size_t align256(size_t v) { return (v + 255) & ~(size_t)255; }

extern "C" void kernel_launch(void* const* d_in, const int* in_sizes, int n_in,
                              void* d_out, int out_size, void* d_ws, size_t ws_size,
                              hipStream_t stream) {
    const float* x       = (const float*)d_in[0];
    const float* w       = (const float*)d_in[1];
    const int*   row_idx = (const int*)d_in[2];
    const int*   col_idx = (const int*)d_in[3];
    float*       out     = (float*)d_out;
    const int    nnz     = in_sizes[1];
    const int    nfeat   = in_sizes[0] / BATCH;
    const int    nchunk  = (nnz + CHUNK - 1) / CHUNK;
    const int    nT      = (nfeat + 63) / 64;

    // ws layout
    const size_t xT_bytes = (size_t)nfeat * 64 * sizeof(u16);                    // 6.4 MB
    size_t o = align256(xT_bytes);
    const size_t sorted_off = o;  o = align256(o + (size_t)nnz * sizeof(u32));   // 8 MB
    const size_t hist2_off  = o;  o = align256(o + (size_t)nchunk * UNITS * sizeof(u32));
    const size_t base2_off  = o;  o = align256(o + (size_t)nchunk * UNITS * sizeof(u32));
    const size_t cs_off     = o;  o = align256(o + (UNITS + 1) * sizeof(u32));

    const int nOut4 = (out_size * 4 + 15) / 16;

    if (ws_size >= o && nfeat <= 65536 && nchunk <= 4096) {
        u16* xT        = (u16*)d_ws;
        u32* sorted    = (u32*)((char*)d_ws + sorted_off);
        u32* hist2     = (u32*)((char*)d_ws + hist2_off);
        u32* base2     = (u32*)((char*)d_ws + base2_off);
        u32* col_start = (u32*)((char*)d_ws + cs_off);

        prep_kernel<<<NZERO + nT + nchunk, 256, 0, stream>>>(
            x, xT, col_idx, hist2, out, nfeat, NZERO, nT, nnz);
        scan_kernel<<<1, 1024, 0, stream>>>(hist2, base2, col_start, nchunk);
        reorder_kernel<<<nchunk, 512, 0, stream>>>(row_idx, col_idx, w, base2,
                                                   sorted, nnz);
        gather_kernel<<<UNITS * NSPLIT, 256, 0, stream>>>(xT, sorted, col_start, out);
    } else if (ws_size >= xT_bytes) {
        u16* xT = (u16*)d_ws;
        prep_kernel<<<NZERO + nT, 256, 0, stream>>>(
            x, xT, col_idx, nullptr, out, nfeat, NZERO, nT, 0);
        scatter_fallback_kernel<<<256, 1024, 32 * UNITS * sizeof(float), stream>>>(
            xT, w, row_idx, col_idx, out, nnz);
    } else {
        zero4_kernel<<<64, 256, 0, stream>>>((uint4*)out, nOut4);
        fallback_kernel<<<2048, 256, 0, stream>>>(x, w, row_idx, col_idx, out, nnz, nfeat);
    }
}

// Round 10
// 162.926 us; speedup vs baseline: 1.0196x; 1.0196x over previous
//
#include <hip/hip_runtime.h>
#include <hip/hip_bf16.h>

#define BATCH 64
#define UNITS 1024
#define CHUNK 8192
#define JB 32          // chunks per scan block

typedef unsigned int u32;
typedef unsigned short u16;

// ---------------- zero helper (fallback paths only) ------------------------
__global__ __launch_bounds__(256)
void zero4_kernel(uint4* __restrict__ p, int n4) {
    int i = blockIdx.x * 256 + threadIdx.x;
    const int stride = gridDim.x * 256;
    const uint4 z = make_uint4(0u, 0u, 0u, 0u);
    for (; i < n4; i += stride) p[i] = z;
}

// ---------------- fused: transpose x -> bf16 xT  AND  per-chunk histogram --
__global__ __launch_bounds__(256)
void prep_kernel(const float* __restrict__ x, u16* __restrict__ xT,
                 const int* __restrict__ col, u32* __restrict__ hist2,
                 int nfeat, int nT, int nnz) {
    __shared__ float tile[64][65];
    __shared__ u32 lh[UNITS];
    const int bid = blockIdx.x;
    const int tid = threadIdx.x;
    if (bid < nT) {
        const int c0 = bid * 64;
        const int tx = tid & 63, ty = tid >> 6;
        for (int b = ty; b < 64; b += 4) {
            int c = c0 + tx;
            if (c < nfeat) tile[b][tx] = x[(size_t)b * nfeat + c];   // coalesced
        }
        __syncthreads();
        for (int i = ty; i < 64; i += 4) {
            int c = c0 + i;
            if (c < nfeat) {
                __hip_bfloat16 h = __float2bfloat16(tile[tx][i]);
                xT[(size_t)c * 64 + tx] = *(u16*)&h;                 // coalesced
            }
        }
    } else {
        const int g = bid - nT;
        for (int i = tid; i < UNITS; i += 256) lh[i] = 0u;
        __syncthreads();
        const int g0 = g * CHUNK;
        const int n = min(CHUNK, nnz - g0);
        for (int i = tid; i < n; i += 256)
            atomicAdd(&lh[col[g0 + i]], 1u);
        __syncthreads();
        for (int c = tid; c < UNITS; c += 256)
            hist2[(size_t)g * UNITS + c] = lh[c];
    }
}

// ---------------- scanA: per-block-of-JB-chunks column partials ------------
__global__ __launch_bounds__(1024)
void scanA_kernel(const u32* __restrict__ hist2, u32* __restrict__ partial,
                  int nchunk) {
    const int j = blockIdx.x, c = threadIdx.x;
    const int gs = j * JB, ge = min(gs + JB, nchunk);
    u32 s = 0;
#pragma unroll 8
    for (int g = gs; g < ge; ++g) s += hist2[(size_t)g * UNITS + c];  // coalesced
    partial[(size_t)j * UNITS + c] = s;
}

// ---------------- scanB: column exclusive scan + per-block bases -----------
__global__ __launch_bounds__(1024)
void scanB_kernel(const u32* __restrict__ partial, u32* __restrict__ jb,
                  u32* __restrict__ col_start, int nblk) {
    const int c = threadIdx.x;
    u32 tot = 0;
    for (int j = 0; j < nblk; ++j) tot += partial[(size_t)j * UNITS + c];
    __shared__ u32 a[UNITS];
    a[c] = tot;
    __syncthreads();
    for (int off = 1; off < UNITS; off <<= 1) {
        u32 add = (c >= off) ? a[c - off] : 0u;
        u32 v = a[c];
        __syncthreads();
        a[c] = v + add;
        __syncthreads();
    }
    u32 run = a[c] - tot;                    // exclusive column prefix
    col_start[c] = run;
    if (c == UNITS - 1) col_start[UNITS] = a[UNITS - 1];
    for (int j = 0; j < nblk; ++j) {
        jb[(size_t)j * UNITS + c] = run;
        run += partial[(size_t)j * UNITS + c];
    }
}

// ---------------- reorder: pack (bf16(w)<<16 | row) into column bins -------
// Base = jb[block-of-chunks] + sum of earlier hist2 rows (<=31 coalesced row
// loads, parallel across 245 WGs). LDS atomics only; 8-deep batched MLP.
__global__ __launch_bounds__(512)
void reorder_kernel(const int* __restrict__ row, const int* __restrict__ col,
                    const float* __restrict__ w, const u32* __restrict__ hist2,
                    const u32* __restrict__ jb, u32* __restrict__ sorted, int nnz) {
    __shared__ u32 cur[UNITS];
    const int tid = threadIdx.x;
    const int g = blockIdx.x;
    const int j = g / JB, gs = j * JB;
    for (int c = tid; c < UNITS; c += 512) {
        u32 v = jb[(size_t)j * UNITS + c];
#pragma unroll 4
        for (int gp = gs; gp < g; ++gp) v += hist2[(size_t)gp * UNITS + c];
        cur[c] = v;
    }
    __syncthreads();
    const int g0 = g * CHUNK;
    const int n = min(CHUNK, nnz - g0);
    if (n == CHUNK) {
        for (int j2 = 0; j2 < CHUNK / 512; j2 += 8) {     // 2 batches of 8
            u32 cc[8], pk[8], lo[8];
#pragma unroll
            for (int q = 0; q < 8; ++q) {
                const int k = g0 + tid + 512 * (j2 + q);
                cc[q] = (u32)col[k];
                __hip_bfloat16 h = __float2bfloat16(w[k]);
                pk[q] = ((u32)(*(const u16*)&h) << 16) | (u32)row[k];
            }
#pragma unroll
            for (int q = 0; q < 8; ++q) lo[q] = atomicAdd(&cur[cc[q]], 1u);
#pragma unroll
            for (int q = 0; q < 8; ++q) sorted[lo[q]] = pk[q];
        }
    } else {
        for (int i = tid; i < n; i += 512) {
            const int k = g0 + i;
            const u32 c = (u32)col[k];
            __hip_bfloat16 h = __float2bfloat16(w[k]);
            const u32 pk = ((u32)(*(const u16*)&h) << 16) | (u32)row[k];
            const u32 lo = atomicAdd(&cur[c], 1u);
            sorted[lo] = pk;
        }
    }
}

// ---------------- gather: batch-half pass, L2-resident ---------------------
// Pass HALF touches only bytes [HALF*64, HALF*64+64) of each 128B xT row ->
// hot set 3.2 MB < 4 MB per-XCD L2. Two launches phase-separate the passes.
// A wave's 64 lanes = 2 entries x 32 batches (entry parity = lane>>5), so
// each VMEM instruction covers two contiguous 64B segments. Entries reach
// lanes via readlane pairs (no dependent index loads). One WG per (column,
// pass) -> plain stores, no zero pass, no atomics.
template<int HALF>
__global__ __launch_bounds__(256)
void gather_half_kernel(const u16* __restrict__ xTu, const u32* __restrict__ sorted,
                        const u32* __restrict__ col_start, float* __restrict__ out) {
    const int u = blockIdx.x;
    const int tid = threadIdx.x;
    const int wv = tid >> 6;
    const int lane = tid & 63;
    const int sub = lane >> 5;          // 0: even entries, 1: odd entries
    const int bl = lane & 31;           // batch within half
    const u32 s = col_start[u], e = col_start[u + 1];
    const u16* xh = xTu + HALF * 32 + bl;   // per-lane base; row offset per entry
    float acc0 = 0.f, acc1 = 0.f, acc2 = 0.f, acc3 = 0.f;
    for (u32 b0 = s + (u32)wv * 64u; b0 < e; b0 += 256u) {
        u32 pk = 0u;                                 // pad: w=+0 -> no-op
        if (b0 + (u32)lane < e) pk = sorted[b0 + (u32)lane];
#pragma unroll
        for (int t = 0; t < 64; t += 8) {            // 4 pairs per group
            u32 ee[4];
#pragma unroll
            for (int q = 0; q < 4; ++q) {
                const u32 ea = (u32)__builtin_amdgcn_readlane((int)pk, t + 2 * q);
                const u32 eb = (u32)__builtin_amdgcn_readlane((int)pk, t + 2 * q + 1);
                ee[q] = sub ? eb : ea;
            }
            float xv[4];
#pragma unroll
            for (int q = 0; q < 4; ++q)
                xv[q] = __uint_as_float(((u32)xh[(size_t)(ee[q] & 0xffffu) << 6]) << 16);
            acc0 = fmaf(xv[0], __uint_as_float(ee[0] & 0xffff0000u), acc0);
            acc1 = fmaf(xv[1], __uint_as_float(ee[1] & 0xffff0000u), acc1);
            acc2 = fmaf(xv[2], __uint_as_float(ee[2] & 0xffff0000u), acc2);
            acc3 = fmaf(xv[3], __uint_as_float(ee[3] & 0xffff0000u), acc3);
        }
    }
    float tot = (acc0 + acc1) + (acc2 + acc3);
    tot += __shfl_xor(tot, 32);                      // combine even/odd entry sums
    __shared__ float red[4][32];
    if (sub == 0) red[wv][bl] = tot;
    __syncthreads();
    if (tid < 32)
        out[(size_t)(HALF * 32 + tid) * UNITS + u] =
            red[0][tid] + red[1][tid] + red[2][tid] + red[3][tid];
}

// ---------------- small-ws fallbacks ---------------------------------------
__global__ __launch_bounds__(1024, 1)
void scatter_fallback_kernel(const u16* __restrict__ xT, const float* __restrict__ w,
                             const int* __restrict__ row_idx, const int* __restrict__ col_idx,
                             float* __restrict__ out, int nnz) {
    extern __shared__ float priv[];
    const int tid = threadIdx.x;
    for (int i = tid; i < 32 * UNITS; i += 1024) priv[i] = 0.0f;
    __syncthreads();
    const int bid = blockIdx.x, half = bid >> 7, wgIdx = bid & 127;
    const int wave = tid >> 6, lane = tid & 63, h = lane >> 5, bl = lane & 31;
    const int per = (nnz + 127) >> 7;
    const int k0 = wgIdx * per, kend = min(k0 + per, nnz);
    const u16* xTh = xT + half * 32 + bl;
    for (int k = k0 + wave * 2 + h; k < kend; k += 32) {
        const int r = row_idx[k], c = col_idx[k];
        const float xv = __uint_as_float(((u32)xTh[(size_t)r * 64]) << 16);
        atomicAdd(&priv[c * 32 + bl], xv * w[k]);
    }
    __syncthreads();
    for (int i = tid; i < 32 * UNITS; i += 1024) {
        int c = i >> 5, b = half * 32 + (i & 31);
        unsafeAtomicAdd(&out[b * UNITS + c], priv[i]);
    }
}

__global__ __launch_bounds__(256)
void fallback_kernel(const float* __restrict__ x, const float* __restrict__ w,
                     const int* __restrict__ row_idx, const int* __restrict__ col_idx,
                     float* __restrict__ out, int nnz, int nfeat) {
    const int nwaves = (gridDim.x * blockDim.x) >> 6;
    const int wid = (blockIdx.x * blockDim.x + threadIdx.x) >> 6;
    const int lane = threadIdx.x & 63;
    for (int k = wid; k < nnz; k += nwaves) {
        const int r = row_idx[k], c = col_idx[k];
        unsafeAtomicAdd(&out[lane * UNITS + c], x[(size_t)lane * nfeat + r] * w[k]);
    }
}

static inline size_t align256(size_t v) { return (v + 255) & ~(size_t)255; }

extern "C" void kernel_launch(void* const* d_in, const int* in_sizes, int n_in,
                              void* d_out, int out_size, void* d_ws, size_t ws_size,
                              hipStream_t stream) {
    const float* x       = (const float*)d_in[0];
    const float* w       = (const float*)d_in[1];
    const int*   row_idx = (const int*)d_in[2];
    const int*   col_idx = (const int*)d_in[3];
    float*       out     = (float*)d_out;
    const int    nnz     = in_sizes[1];
    const int    nfeat   = in_sizes[0] / BATCH;
    const int    nchunk  = (nnz + CHUNK - 1) / CHUNK;
    const int    nblk    = (nchunk + JB - 1) / JB;
    const int    nT      = (nfeat + 63) / 64;

    // ws layout
    const size_t xT_bytes = (size_t)nfeat * 64 * sizeof(u16);                    // 6.4 MB
    size_t o = align256(xT_bytes);
    const size_t sorted_off = o;  o = align256(o + (size_t)nnz * sizeof(u32));   // 8 MB
    const size_t hist2_off  = o;  o = align256(o + (size_t)nchunk * UNITS * sizeof(u32));
    const size_t part_off   = o;  o = align256(o + (size_t)nblk * UNITS * sizeof(u32));
    const size_t jb_off     = o;  o = align256(o + (size_t)nblk * UNITS * sizeof(u32));
    const size_t cs_off     = o;  o = align256(o + (UNITS + 1) * sizeof(u32));

    const int nOut4 = (out_size * 4 + 15) / 16;

    if (ws_size >= o && nfeat <= 65536 && nblk <= 64) {
        u16* xT        = (u16*)d_ws;
        u32* sorted    = (u32*)((char*)d_ws + sorted_off);
        u32* hist2     = (u32*)((char*)d_ws + hist2_off);
        u32* partial   = (u32*)((char*)d_ws + part_off);
        u32* jb        = (u32*)((char*)d_ws + jb_off);
        u32* col_start = (u32*)((char*)d_ws + cs_off);

        prep_kernel<<<nT + nchunk, 256, 0, stream>>>(x, xT, col_idx, hist2,
                                                     nfeat, nT, nnz);
        scanA_kernel<<<nblk, 1024, 0, stream>>>(hist2, partial, nchunk);
        scanB_kernel<<<1, 1024, 0, stream>>>(partial, jb, col_start, nblk);
        reorder_kernel<<<nchunk, 512, 0, stream>>>(row_idx, col_idx, w, hist2,
                                                   jb, sorted, nnz);
        gather_half_kernel<0><<<UNITS, 256, 0, stream>>>(xT, sorted, col_start, out);
        gather_half_kernel<1><<<UNITS, 256, 0, stream>>>(xT, sorted, col_start, out);
    } else if (ws_size >= xT_bytes) {
        u16* xT = (u16*)d_ws;
        zero4_kernel<<<64, 256, 0, stream>>>((uint4*)out, nOut4);
        prep_kernel<<<nT, 256, 0, stream>>>(x, xT, col_idx, nullptr, nfeat, nT, 0);
        scatter_fallback_kernel<<<256, 1024, 32 * UNITS * sizeof(float), stream>>>(
            xT, w, row_idx, col_idx, out, nnz);
    } else {
        zero4_kernel<<<64, 256, 0, stream>>>((uint4*)out, nOut4);
        fallback_kernel<<<2048, 256, 0, stream>>>(x, w, row_idx, col_idx, out, nnz, nfeat);
    }
}

// Round 11
// 147.725 us; speedup vs baseline: 1.1246x; 1.1029x over previous
//
#include <hip/hip_runtime.h>
#include <hip/hip_bf16.h>

#define BATCH 64
#define UNITS 1024
#define CHUNK 16384

typedef unsigned int u32;
typedef unsigned short u16;

// ---------------- zero helper (fallback paths only) ------------------------
__global__ __launch_bounds__(256)
void zero4_kernel(uint4* __restrict__ p, int n4) {
    int i = blockIdx.x * 256 + threadIdx.x;
    const int stride = gridDim.x * 256;
    const uint4 z = make_uint4(0u, 0u, 0u, 0u);
    for (; i < n4; i += stride) p[i] = z;
}

// ---------------- fused: transpose x -> bf16 xT  AND  per-chunk histogram --
__global__ __launch_bounds__(256)
void prep_kernel(const float* __restrict__ x, u16* __restrict__ xT,
                 const int* __restrict__ col, u32* __restrict__ hist2,
                 int nfeat, int nT, int nnz) {
    __shared__ float tile[64][65];
    __shared__ u32 lh[UNITS];
    const int bid = blockIdx.x;
    const int tid = threadIdx.x;
    if (bid < nT) {
        const int c0 = bid * 64;
        const int tx = tid & 63, ty = tid >> 6;
        for (int b = ty; b < 64; b += 4) {
            int c = c0 + tx;
            if (c < nfeat) tile[b][tx] = x[(size_t)b * nfeat + c];   // coalesced
        }
        __syncthreads();
        for (int i = ty; i < 64; i += 4) {
            int c = c0 + i;
            if (c < nfeat) {
                __hip_bfloat16 h = __float2bfloat16(tile[tx][i]);
                xT[(size_t)c * 64 + tx] = *(u16*)&h;                 // coalesced
            }
        }
    } else {
        const int g = bid - nT;
        for (int i = tid; i < UNITS; i += 256) lh[i] = 0u;
        __syncthreads();
        const int g0 = g * CHUNK;
        const int n = min(CHUNK, nnz - g0);
        for (int i = tid; i < n; i += 256)
            atomicAdd(&lh[col[g0 + i]], 1u);
        __syncthreads();
        for (int c = tid; c < UNITS; c += 256)
            hist2[(size_t)g * UNITS + c] = lh[c];
    }
}

// ---- reorder with FUSED scan: replaces scanA + scanB + base prologue ------
// Every WG reads the whole hist2 matrix once (nchunk coalesced row loads,
// L2-broadcast), accumulating per-column total and prefix-before-g in one
// pass; then an identical deterministic 1024-wide LDS scan gives the global
// column offsets. WG 0 also emits col_start for the gather. Then the batched
// LDS-cursor scatter packs (bf16(w)<<16 | row) into column bins.
__global__ __launch_bounds__(1024)
void reorder_scan_kernel(const int* __restrict__ row, const int* __restrict__ col,
                         const float* __restrict__ w, const u32* __restrict__ hist2,
                         u32* __restrict__ col_start, u32* __restrict__ sorted,
                         int nchunk, int nnz) {
    __shared__ u32 aA[UNITS], aB[UNITS], cur[UNITS];
    const int c = threadIdx.x;          // thread = column
    const int g = blockIdx.x;           // WG = chunk
    u32 tot = 0, pre = 0;
    int gp = 0;
    for (; gp + 4 <= nchunk; gp += 4) {     // independent coalesced row loads
        const u32 h0 = hist2[(size_t)(gp + 0) * UNITS + c];
        const u32 h1 = hist2[(size_t)(gp + 1) * UNITS + c];
        const u32 h2 = hist2[(size_t)(gp + 2) * UNITS + c];
        const u32 h3 = hist2[(size_t)(gp + 3) * UNITS + c];
        tot += (h0 + h1) + (h2 + h3);
        pre += (gp + 0 < g ? h0 : 0u) + (gp + 1 < g ? h1 : 0u) +
               (gp + 2 < g ? h2 : 0u) + (gp + 3 < g ? h3 : 0u);
    }
    for (; gp < nchunk; ++gp) {
        const u32 h = hist2[(size_t)gp * UNITS + c];
        tot += h;
        if (gp < g) pre += h;
    }
    aA[c] = tot;
    __syncthreads();
    u32* src = aA;
    u32* dst = aB;
    for (int off = 1; off < UNITS; off <<= 1) {   // Hillis-Steele, ping-pong
        dst[c] = src[c] + ((c >= off) ? src[c - off] : 0u);
        __syncthreads();
        u32* t = src; src = dst; dst = t;
    }
    const u32 incl = src[c];
    const u32 excl = incl - tot;
    cur[c] = excl + pre;
    if (g == 0) {
        col_start[c] = excl;
        if (c == UNITS - 1) col_start[UNITS] = incl;
    }
    __syncthreads();
    const int g0 = g * CHUNK;
    const int n = min(CHUNK, nnz - g0);
    if (n == CHUNK) {
        for (int j2 = 0; j2 < CHUNK / 1024; j2 += 8) {    // 2 batches of 8
            u32 cc[8], pk[8], lo[8];
#pragma unroll
            for (int q = 0; q < 8; ++q) {
                const int k = g0 + c + 1024 * (j2 + q);
                cc[q] = (u32)col[k];
                __hip_bfloat16 h = __float2bfloat16(w[k]);
                pk[q] = ((u32)(*(const u16*)&h) << 16) | (u32)row[k];
            }
#pragma unroll
            for (int q = 0; q < 8; ++q) lo[q] = atomicAdd(&cur[cc[q]], 1u);
#pragma unroll
            for (int q = 0; q < 8; ++q) sorted[lo[q]] = pk[q];
        }
    } else {
        for (int i = c; i < n; i += 1024) {
            const int k = g0 + i;
            const u32 cc = (u32)col[k];
            __hip_bfloat16 h = __float2bfloat16(w[k]);
            const u32 pk = ((u32)(*(const u16*)&h) << 16) | (u32)row[k];
            const u32 lo = atomicAdd(&cur[cc], 1u);
            sorted[lo] = pk;
        }
    }
}

// ---- gather: one column per WG, 64 batches = 64 lanes (round-7 verbatim) --
__global__ __launch_bounds__(256)
void gather_kernel(const u16* __restrict__ xTu, const u32* __restrict__ sorted,
                   const u32* __restrict__ col_start, float* __restrict__ out) {
    const int u = blockIdx.x;
    const int tid = threadIdx.x;
    const int wv = tid >> 6, lane = tid & 63;       // lane = batch
    const u32 s = col_start[u], e = col_start[u + 1];
    float acc0 = 0.f, acc1 = 0.f, acc2 = 0.f, acc3 = 0.f;
    for (u32 b0 = s + (u32)wv * 64u; b0 < e; b0 += 256u) {
        u32 pk = 0u;                                 // pad: w=+0 -> no-op
        if (b0 + (u32)lane < e) pk = sorted[b0 + (u32)lane];
#pragma unroll
        for (int t = 0; t < 64; t += 4) {
            const u32 e0 = (u32)__builtin_amdgcn_readlane((int)pk, t);
            const u32 e1 = (u32)__builtin_amdgcn_readlane((int)pk, t + 1);
            const u32 e2 = (u32)__builtin_amdgcn_readlane((int)pk, t + 2);
            const u32 e3 = (u32)__builtin_amdgcn_readlane((int)pk, t + 3);
            const float x0 = __uint_as_float(((u32)xTu[(size_t)(e0 & 0xffffu) * 64 + lane]) << 16);
            const float x1 = __uint_as_float(((u32)xTu[(size_t)(e1 & 0xffffu) * 64 + lane]) << 16);
            const float x2 = __uint_as_float(((u32)xTu[(size_t)(e2 & 0xffffu) * 64 + lane]) << 16);
            const float x3 = __uint_as_float(((u32)xTu[(size_t)(e3 & 0xffffu) * 64 + lane]) << 16);
            acc0 = fmaf(x0, __uint_as_float(e0 & 0xffff0000u), acc0);
            acc1 = fmaf(x1, __uint_as_float(e1 & 0xffff0000u), acc1);
            acc2 = fmaf(x2, __uint_as_float(e2 & 0xffff0000u), acc2);
            acc3 = fmaf(x3, __uint_as_float(e3 & 0xffff0000u), acc3);
        }
    }
    float tot = (acc0 + acc1) + (acc2 + acc3);
    __shared__ float red[4][64];
    red[wv][lane] = tot;
    __syncthreads();
    if (wv == 0)
        out[(size_t)lane * UNITS + u] =
            red[0][lane] + red[1][lane] + red[2][lane] + red[3][lane];
}

// ---------------- small-ws fallbacks ---------------------------------------
__global__ __launch_bounds__(1024, 1)
void scatter_fallback_kernel(const u16* __restrict__ xT, const float* __restrict__ w,
                             const int* __restrict__ row_idx, const int* __restrict__ col_idx,
                             float* __restrict__ out, int nnz) {
    extern __shared__ float priv[];
    const int tid = threadIdx.x;
    for (int i = tid; i < 32 * UNITS; i += 1024) priv[i] = 0.0f;
    __syncthreads();
    const int bid = blockIdx.x, half = bid >> 7, wgIdx = bid & 127;
    const int wave = tid >> 6, lane = tid & 63, h = lane >> 5, bl = lane & 31;
    const int per = (nnz + 127) >> 7;
    const int k0 = wgIdx * per, kend = min(k0 + per, nnz);
    const u16* xTh = xT + half * 32 + bl;
    for (int k = k0 + wave * 2 + h; k < kend; k += 32) {
        const int r = row_idx[k], c = col_idx[k];
        const float xv = __uint_as_float(((u32)xTh[(size_t)r * 64]) << 16);
        atomicAdd(&priv[c * 32 + bl], xv * w[k]);
    }
    __syncthreads();
    for (int i = tid; i < 32 * UNITS; i += 1024) {
        int c = i >> 5, b = half * 32 + (i & 31);
        unsafeAtomicAdd(&out[b * UNITS + c], priv[i]);
    }
}

__global__ __launch_bounds__(256)
void fallback_kernel(const float* __restrict__ x, const float* __restrict__ w,
                     const int* __restrict__ row_idx, const int* __restrict__ col_idx,
                     float* __restrict__ out, int nnz, int nfeat) {
    const int nwaves = (gridDim.x * blockDim.x) >> 6;
    const int wid = (blockIdx.x * blockDim.x + threadIdx.x) >> 6;
    const int lane = threadIdx.x & 63;
    for (int k = wid; k < nnz; k += nwaves) {
        const int r = row_idx[k], c = col_idx[k];
        unsafeAtomicAdd(&out[lane * UNITS + c], x[(size_t)lane * nfeat + r] * w[k]);
    }
}

static inline size_t align256(size_t v) { return (v + 255) & ~(size_t)255; }

extern "C" void kernel_launch(void* const* d_in, const int* in_sizes, int n_in,
                              void* d_out, int out_size, void* d_ws, size_t ws_size,
                              hipStream_t stream) {
    const float* x       = (const float*)d_in[0];
    const float* w       = (const float*)d_in[1];
    const int*   row_idx = (const int*)d_in[2];
    const int*   col_idx = (const int*)d_in[3];
    float*       out     = (float*)d_out;
    const int    nnz     = in_sizes[1];
    const int    nfeat   = in_sizes[0] / BATCH;
    const int    nchunk  = (nnz + CHUNK - 1) / CHUNK;
    const int    nT      = (nfeat + 63) / 64;

    // ws layout
    const size_t xT_bytes = (size_t)nfeat * 64 * sizeof(u16);                    // 6.4 MB
    size_t o = align256(xT_bytes);
    const size_t sorted_off = o;  o = align256(o + (size_t)nnz * sizeof(u32));   // 8 MB
    const size_t hist2_off  = o;  o = align256(o + (size_t)nchunk * UNITS * sizeof(u32));
    const size_t cs_off     = o;  o = align256(o + (UNITS + 1) * sizeof(u32));

    const int nOut4 = (out_size * 4 + 15) / 16;

    if (ws_size >= o && nfeat <= 65536 && nchunk <= 2048) {
        u16* xT        = (u16*)d_ws;
        u32* sorted    = (u32*)((char*)d_ws + sorted_off);
        u32* hist2     = (u32*)((char*)d_ws + hist2_off);
        u32* col_start = (u32*)((char*)d_ws + cs_off);

        prep_kernel<<<nT + nchunk, 256, 0, stream>>>(x, xT, col_idx, hist2,
                                                     nfeat, nT, nnz);
        reorder_scan_kernel<<<nchunk, 1024, 0, stream>>>(
            row_idx, col_idx, w, hist2, col_start, sorted, nchunk, nnz);
        gather_kernel<<<UNITS, 256, 0, stream>>>(xT, sorted, col_start, out);
    } else if (ws_size >= xT_bytes) {
        u16* xT = (u16*)d_ws;
        zero4_kernel<<<64, 256, 0, stream>>>((uint4*)out, nOut4);
        prep_kernel<<<nT, 256, 0, stream>>>(x, xT, col_idx, nullptr, nfeat, nT, 0);
        scatter_fallback_kernel<<<256, 1024, 32 * UNITS * sizeof(float), stream>>>(
            xT, w, row_idx, col_idx, out, nnz);
    } else {
        zero4_kernel<<<64, 256, 0, stream>>>((uint4*)out, nOut4);
        fallback_kernel<<<2048, 256, 0, stream>>>(x, w, row_idx, col_idx, out, nnz, nfeat);
    }
}

// Round 12
// 147.561 us; speedup vs baseline: 1.1258x; 1.0011x over previous
//
#include <hip/hip_runtime.h>
#include <hip/hip_bf16.h>

#define BATCH 64
#define UNITS 1024
#define CHUNK 16384

typedef unsigned int u32;
typedef unsigned short u16;

// ---------------- zero helper (fallback paths only) ------------------------
__global__ __launch_bounds__(256)
void zero4_kernel(uint4* __restrict__ p, int n4) {
    int i = blockIdx.x * 256 + threadIdx.x;
    const int stride = gridDim.x * 256;
    const uint4 z = make_uint4(0u, 0u, 0u, 0u);
    for (; i < n4; i += stride) p[i] = z;
}

// ---------------- fused: transpose x -> bf16 xT  AND  per-chunk histogram --
__global__ __launch_bounds__(256)
void prep_kernel(const float* __restrict__ x, u16* __restrict__ xT,
                 const int* __restrict__ col, u32* __restrict__ hist2,
                 int nfeat, int nT, int nnz) {
    __shared__ float tile[64][65];
    __shared__ u32 lh[UNITS];
    const int bid = blockIdx.x;
    const int tid = threadIdx.x;
    if (bid < nT) {
        const int c0 = bid * 64;
        const int tx = tid & 63, ty = tid >> 6;
        for (int b = ty; b < 64; b += 4) {
            int c = c0 + tx;
            if (c < nfeat) tile[b][tx] = x[(size_t)b * nfeat + c];   // coalesced
        }
        __syncthreads();
        for (int i = ty; i < 64; i += 4) {
            int c = c0 + i;
            if (c < nfeat) {
                __hip_bfloat16 h = __float2bfloat16(tile[tx][i]);
                xT[(size_t)c * 64 + tx] = *(u16*)&h;                 // coalesced
            }
        }
    } else {
        const int g = bid - nT;
        for (int i = tid; i < UNITS; i += 256) lh[i] = 0u;
        __syncthreads();
        const int g0 = g * CHUNK;
        const int n = min(CHUNK, nnz - g0);
        for (int i = tid; i < n; i += 256)
            atomicAdd(&lh[col[g0 + i]], 1u);
        __syncthreads();
        for (int c = tid; c < UNITS; c += 256)
            hist2[(size_t)g * UNITS + c] = lh[c];
    }
}

// ---- reorder with FUSED scan (round-11 verbatim) --------------------------
__global__ __launch_bounds__(1024)
void reorder_scan_kernel(const int* __restrict__ row, const int* __restrict__ col,
                         const float* __restrict__ w, const u32* __restrict__ hist2,
                         u32* __restrict__ col_start, u32* __restrict__ sorted,
                         int nchunk, int nnz) {
    __shared__ u32 aA[UNITS], aB[UNITS], cur[UNITS];
    const int c = threadIdx.x;          // thread = column
    const int g = blockIdx.x;           // WG = chunk
    u32 tot = 0, pre = 0;
    int gp = 0;
    for (; gp + 4 <= nchunk; gp += 4) {     // independent coalesced row loads
        const u32 h0 = hist2[(size_t)(gp + 0) * UNITS + c];
        const u32 h1 = hist2[(size_t)(gp + 1) * UNITS + c];
        const u32 h2 = hist2[(size_t)(gp + 2) * UNITS + c];
        const u32 h3 = hist2[(size_t)(gp + 3) * UNITS + c];
        tot += (h0 + h1) + (h2 + h3);
        pre += (gp + 0 < g ? h0 : 0u) + (gp + 1 < g ? h1 : 0u) +
               (gp + 2 < g ? h2 : 0u) + (gp + 3 < g ? h3 : 0u);
    }
    for (; gp < nchunk; ++gp) {
        const u32 h = hist2[(size_t)gp * UNITS + c];
        tot += h;
        if (gp < g) pre += h;
    }
    aA[c] = tot;
    __syncthreads();
    u32* src = aA;
    u32* dst = aB;
    for (int off = 1; off < UNITS; off <<= 1) {   // Hillis-Steele, ping-pong
        dst[c] = src[c] + ((c >= off) ? src[c - off] : 0u);
        __syncthreads();
        u32* t = src; src = dst; dst = t;
    }
    const u32 incl = src[c];
    const u32 excl = incl - tot;
    cur[c] = excl + pre;
    if (g == 0) {
        col_start[c] = excl;
        if (c == UNITS - 1) col_start[UNITS] = incl;
    }
    __syncthreads();
    const int g0 = g * CHUNK;
    const int n = min(CHUNK, nnz - g0);
    if (n == CHUNK) {
        for (int j2 = 0; j2 < CHUNK / 1024; j2 += 8) {    // 2 batches of 8
            u32 cc[8], pk[8], lo[8];
#pragma unroll
            for (int q = 0; q < 8; ++q) {
                const int k = g0 + c + 1024 * (j2 + q);
                cc[q] = (u32)col[k];
                __hip_bfloat16 h = __float2bfloat16(w[k]);
                pk[q] = ((u32)(*(const u16*)&h) << 16) | (u32)row[k];
            }
#pragma unroll
            for (int q = 0; q < 8; ++q) lo[q] = atomicAdd(&cur[cc[q]], 1u);
#pragma unroll
            for (int q = 0; q < 8; ++q) sorted[lo[q]] = pk[q];
        }
    } else {
        for (int i = c; i < n; i += 1024) {
            const int k = g0 + i;
            const u32 cc = (u32)col[k];
            __hip_bfloat16 h = __float2bfloat16(w[k]);
            const u32 pk = ((u32)(*(const u16*)&h) << 16) | (u32)row[k];
            const u32 lo = atomicAdd(&cur[cc], 1u);
            sorted[lo] = pk;
        }
    }
}

// ---- gather: u32-pair loads — 2 entries per VMEM instruction --------------
// xT viewed as u32[nfeat][32]: lane bl handles batches (2bl, 2bl+1) with one
// dword load; lanes 0-31 process even-parity entries, 32-63 odd (readlane
// pair + cndmask). One VMEM instr covers 2 entries x 128B -> 1M VMEM instrs
// total (vs 2M in the per-entry-ushort form). Single pass, plain stores.
__global__ __launch_bounds__(256)
void gather_kernel(const u32* __restrict__ xTu32, const u32* __restrict__ sorted,
                   const u32* __restrict__ col_start, float* __restrict__ out) {
    const int u = blockIdx.x;
    const int tid = threadIdx.x;
    const int wv = tid >> 6;
    const int lane = tid & 63;
    const int sub = lane >> 5;          // 0: even entries, 1: odd entries
    const int bl = lane & 31;           // u32 word = batches (2bl, 2bl+1)
    const u32 s = col_start[u], e = col_start[u + 1];
    const u32* xb = xTu32 + bl;         // per-lane base; row offset per entry
    float accA0 = 0.f, accA1 = 0.f, accA2 = 0.f, accA3 = 0.f;  // batch 2bl
    float accB0 = 0.f, accB1 = 0.f, accB2 = 0.f, accB3 = 0.f;  // batch 2bl+1
    for (u32 b0 = s + (u32)wv * 64u; b0 < e; b0 += 256u) {
        u32 pk = 0u;                                 // pad: w=+0 -> no-op
        if (b0 + (u32)lane < e) pk = sorted[b0 + (u32)lane];
#pragma unroll
        for (int t = 0; t < 64; t += 8) {            // 4 entry-pairs per group
            u32 ee[4];
#pragma unroll
            for (int q = 0; q < 4; ++q) {
                const u32 ea = (u32)__builtin_amdgcn_readlane((int)pk, t + 2 * q);
                const u32 eb = (u32)__builtin_amdgcn_readlane((int)pk, t + 2 * q + 1);
                ee[q] = sub ? eb : ea;
            }
            u32 xv[4];
#pragma unroll
            for (int q = 0; q < 4; ++q)
                xv[q] = xb[(size_t)(ee[q] & 0xffffu) << 5];   // dword gather
            const float w0 = __uint_as_float(ee[0] & 0xffff0000u);
            const float w1 = __uint_as_float(ee[1] & 0xffff0000u);
            const float w2 = __uint_as_float(ee[2] & 0xffff0000u);
            const float w3 = __uint_as_float(ee[3] & 0xffff0000u);
            accA0 = fmaf(__uint_as_float(xv[0] << 16), w0, accA0);
            accB0 = fmaf(__uint_as_float(xv[0] & 0xffff0000u), w0, accB0);
            accA1 = fmaf(__uint_as_float(xv[1] << 16), w1, accA1);
            accB1 = fmaf(__uint_as_float(xv[1] & 0xffff0000u), w1, accB1);
            accA2 = fmaf(__uint_as_float(xv[2] << 16), w2, accA2);
            accB2 = fmaf(__uint_as_float(xv[2] & 0xffff0000u), w2, accB2);
            accA3 = fmaf(__uint_as_float(xv[3] << 16), w3, accA3);
            accB3 = fmaf(__uint_as_float(xv[3] & 0xffff0000u), w3, accB3);
        }
    }
    float totA = (accA0 + accA1) + (accA2 + accA3);
    float totB = (accB0 + accB1) + (accB2 + accB3);
    totA += __shfl_xor(totA, 32);                    // combine entry parities
    totB += __shfl_xor(totB, 32);
    __shared__ float redA[4][32], redB[4][32];
    if (sub == 0) { redA[wv][bl] = totA; redB[wv][bl] = totB; }
    __syncthreads();
    if (tid < 32) {
        const float sA = redA[0][tid] + redA[1][tid] + redA[2][tid] + redA[3][tid];
        const float sB = redB[0][tid] + redB[1][tid] + redB[2][tid] + redB[3][tid];
        out[(size_t)(2 * tid) * UNITS + u] = sA;
        out[(size_t)(2 * tid + 1) * UNITS + u] = sB;
    }
}

// ---------------- small-ws fallbacks ---------------------------------------
__global__ __launch_bounds__(1024, 1)
void scatter_fallback_kernel(const u16* __restrict__ xT, const float* __restrict__ w,
                             const int* __restrict__ row_idx, const int* __restrict__ col_idx,
                             float* __restrict__ out, int nnz) {
    extern __shared__ float priv[];
    const int tid = threadIdx.x;
    for (int i = tid; i < 32 * UNITS; i += 1024) priv[i] = 0.0f;
    __syncthreads();
    const int bid = blockIdx.x, half = bid >> 7, wgIdx = bid & 127;
    const int wave = tid >> 6, lane = tid & 63, h = lane >> 5, bl = lane & 31;
    const int per = (nnz + 127) >> 7;
    const int k0 = wgIdx * per, kend = min(k0 + per, nnz);
    const u16* xTh = xT + half * 32 + bl;
    for (int k = k0 + wave * 2 + h; k < kend; k += 32) {
        const int r = row_idx[k], c = col_idx[k];
        const float xv = __uint_as_float(((u32)xTh[(size_t)r * 64]) << 16);
        atomicAdd(&priv[c * 32 + bl], xv * w[k]);
    }
    __syncthreads();
    for (int i = tid; i < 32 * UNITS; i += 1024) {
        int c = i >> 5, b = half * 32 + (i & 31);
        unsafeAtomicAdd(&out[b * UNITS + c], priv[i]);
    }
}

__global__ __launch_bounds__(256)
void fallback_kernel(const float* __restrict__ x, const float* __restrict__ w,
                     const int* __restrict__ row_idx, const int* __restrict__ col_idx,
                     float* __restrict__ out, int nnz, int nfeat) {
    const int nwaves = (gridDim.x * blockDim.x) >> 6;
    const int wid = (blockIdx.x * blockDim.x + threadIdx.x) >> 6;
    const int lane = threadIdx.x & 63;
    for (int k = wid; k < nnz; k += nwaves) {
        const int r = row_idx[k], c = col_idx[k];
        unsafeAtomicAdd(&out[lane * UNITS + c], x[(size_t)lane * nfeat + r] * w[k]);
    }
}

static inline size_t align256(size_t v) { return (v + 255) & ~(size_t)255; }

extern "C" void kernel_launch(void* const* d_in, const int* in_sizes, int n_in,
                              void* d_out, int out_size, void* d_ws, size_t ws_size,
                              hipStream_t stream) {
    const float* x       = (const float*)d_in[0];
    const float* w       = (const float*)d_in[1];
    const int*   row_idx = (const int*)d_in[2];
    const int*   col_idx = (const int*)d_in[3];
    float*       out     = (float*)d_out;
    const int    nnz     = in_sizes[1];
    const int    nfeat   = in_sizes[0] / BATCH;
    const int    nchunk  = (nnz + CHUNK - 1) / CHUNK;
    const int    nT      = (nfeat + 63) / 64;

    // ws layout
    const size_t xT_bytes = (size_t)nfeat * 64 * sizeof(u16);                    // 6.4 MB
    size_t o = align256(xT_bytes);
    const size_t sorted_off = o;  o = align256(o + (size_t)nnz * sizeof(u32));   // 8 MB
    const size_t hist2_off  = o;  o = align256(o + (size_t)nchunk * UNITS * sizeof(u32));
    const size_t cs_off     = o;  o = align256(o + (UNITS + 1) * sizeof(u32));

    const int nOut4 = (out_size * 4 + 15) / 16;

    if (ws_size >= o && nfeat <= 65536 && nchunk <= 2048) {
        u16* xT        = (u16*)d_ws;
        u32* sorted    = (u32*)((char*)d_ws + sorted_off);
        u32* hist2     = (u32*)((char*)d_ws + hist2_off);
        u32* col_start = (u32*)((char*)d_ws + cs_off);

        prep_kernel<<<nT + nchunk, 256, 0, stream>>>(x, xT, col_idx, hist2,
                                                     nfeat, nT, nnz);
        reorder_scan_kernel<<<nchunk, 1024, 0, stream>>>(
            row_idx, col_idx, w, hist2, col_start, sorted, nchunk, nnz);
        gather_kernel<<<UNITS, 256, 0, stream>>>((const u32*)xT, sorted,
                                                 col_start, out);
    } else if (ws_size >= xT_bytes) {
        u16* xT = (u16*)d_ws;
        zero4_kernel<<<64, 256, 0, stream>>>((uint4*)out, nOut4);
        prep_kernel<<<nT, 256, 0, stream>>>(x, xT, col_idx, nullptr, nfeat, nT, 0);
        scatter_fallback_kernel<<<256, 1024, 32 * UNITS * sizeof(float), stream>>>(
            xT, w, row_idx, col_idx, out, nnz);
    } else {
        zero4_kernel<<<64, 256, 0, stream>>>((uint4*)out, nOut4);
        fallback_kernel<<<2048, 256, 0, stream>>>(x, w, row_idx, col_idx, out, nnz, nfeat);
    }
}